// Round 5
// baseline (1129.825 us; speedup 1.0000x reference)
//
#include <hip/hip_runtime.h>
#include <stdint.h>

// Window attention, Swin-style. B=4096 windows, N=49, C=256, NH=8, D=32.
// FULLY FUSED v4: one block per window (512 thr, 8 waves), wave w owns head w.
// Weights stream from L2 straight into MFMA fragments (no staging LDS).
// LDS cut to ~73 KB (per-wave time-shared scratch for Q/K/V^T/P + XS/AO alias)
// -> 2 blocks/CU, 4 waves/SIMD for latency hiding. 3 barriers total.

typedef __attribute__((ext_vector_type(8))) short bf16x8;
typedef __attribute__((ext_vector_type(4))) float f32x4;

__device__ __forceinline__ unsigned short f2bf(float f) {
    unsigned u = __float_as_uint(f);
    u += 0x7fffu + ((u >> 16) & 1u);   // RNE
    return (unsigned short)(u >> 16);
}
__device__ __forceinline__ unsigned pk2(float a, float b) {
    return (unsigned)f2bf(a) | ((unsigned)f2bf(b) << 16);
}

// ---- K0: weights fp32 -> bf16, transposed to [feat][k] (B^T) layout ----
__global__ void k_prep(const float* __restrict__ qkv_w, const float* __restrict__ proj_w,
                       short* __restrict__ Wqkv_t, short* __restrict__ Wproj_t) {
    int tid = blockIdx.x * 256 + threadIdx.x;   // 262144 total
    if (tid < 196608) {                          // 768*256
        int nn = tid >> 8, kk = tid & 255;
        Wqkv_t[tid] = (short)f2bf(qkv_w[kk * 768 + nn]);
    } else {
        int t2 = tid - 196608;                   // 256*256
        int nn = t2 >> 8, kk = t2 & 255;
        Wproj_t[t2] = (short)f2bf(proj_w[kk * 256 + nn]);
    }
}

// LDS map (shorts). Total 34816 shorts (69632 B) + rpbs 5408 B = 75040 B -> 2 blocks/CU.
//   XS @ 0      [64tok][256k] (chunk-swz) 32 KB   } aliased: XS dead after phase-1
//   AO @ 0      [8h][64tok][32d] (chunk-swz)      } K-loop (barrier #2 separates)
//   SW @ 16384  per-wave 2304-short scratch, time-shared:
//               stage Q[64][32] (2048) -> q-frags -> K[64][32] -> k-frags
//               -> V^T[32][72] (2304) -> v-frags -> P[16][72] (1152)
#define XS_OFF 0
#define AO_OFF 0
#define SW_OFF 16384

__global__ __launch_bounds__(512, 4) void k_fused(
        const float* __restrict__ x, const short* __restrict__ Wq,
        const short* __restrict__ Wp, const float* __restrict__ qkv_b,
        const float* __restrict__ rpb, const float* __restrict__ proj_b,
        float* __restrict__ out) {
    __shared__ __align__(16) short smem[34816];
    __shared__ float rpbs[1352];               // [8h][169] per-head contiguous

    const int b = blockIdx.x;
    const int t = threadIdx.x;
    const int w = t >> 6, lane = t & 63;
    const int l15 = lane & 15, g = lane >> 4;
    const int cs8 = (l15 >> 1) & 3;               // chunk-swz field for 32-short rows
    const int swz = (g ^ cs8) << 3;               // swizzled frag chunk offset

    f32x4 zero = {0.f, 0.f, 0.f, 0.f};

    // ---- phase 0: rpb -> LDS (transposed to [h][169]); x fp32 -> bf16 -> XS ----
    for (int i = t; i < 1352; i += 512) rpbs[(i & 7) * 169 + (i >> 3)] = rpb[i];
    #pragma unroll
    for (int i = 0; i < 4; i++) {
        int cid = t + i * 512;                    // 2048 granules = 64 tok x 32 chunks
        int tok = cid >> 5, c = cid & 31;
        uint4 w4 = make_uint4(0u, 0u, 0u, 0u);
        if (tok < 49) {
            const float4* s = (const float4*)(x + ((size_t)b * 49 + tok) * 256 + c * 8);
            float4 f0 = s[0], f1 = s[1];
            w4 = make_uint4(pk2(f0.x, f0.y), pk2(f0.z, f0.w),
                            pk2(f1.x, f1.y), pk2(f1.z, f1.w));
        }
        *(uint4*)&smem[XS_OFF + tok * 256 + ((c ^ (tok & 7)) << 3)] = w4;
    }
    __syncthreads();   // barrier #1: XS + rpbs visible

    // ---- phase 1: QKV GEMM. Wave w computes Q,K,V of head w (96 feats x 64 tok).
    //      A-frags (weights) straight from L2; B-frags from XS. No barriers. ----
    f32x4 acc[6][4];                              // [p*2+it][tok quadrant]
    #pragma unroll
    for (int i = 0; i < 6; i++)
        #pragma unroll
        for (int j = 0; j < 4; j++) acc[i][j] = zero;
    {
        const short* wbase = Wq + (size_t)(w * 32 + l15) * 256 + g * 8;
        #pragma unroll
        for (int ks = 0; ks < 8; ks++) {
            bf16x8 af[6], bfj[4];
            #pragma unroll
            for (int p = 0; p < 3; p++)
                #pragma unroll
                for (int it = 0; it < 2; it++)
                    af[p * 2 + it] = *(const bf16x8*)(wbase + p * 65536 + it * 4096 + ks * 32);
            int xsl = (((ks << 2) + g) ^ (l15 & 7)) << 3;
            #pragma unroll
            for (int j = 0; j < 4; j++)
                bfj[j] = *(const bf16x8*)&smem[XS_OFF + (j * 16 + l15) * 256 + xsl];
            #pragma unroll
            for (int i = 0; i < 6; i++)
                #pragma unroll
                for (int j = 0; j < 4; j++)
                    acc[i][j] = __builtin_amdgcn_mfma_f32_16x16x32_bf16(
                        af[i], bfj[j], acc[i][j], 0, 0, 0);
        }
    }
    __syncthreads();   // barrier #2: all XS reads done (AO aliases XS below)

    // ---- phase 1b + 2: wave-local epilogue + attention, head h = w ----
    {
        const int h = w;
        short* SW = &smem[SW_OFF + w * 2304];     // per-wave scratch
        const int d0a = g * 4;                    // it=0 feature base
        const int d0b = 16 + g * 4;               // it=1 feature base
        const int sda = (((d0a >> 3) ^ cs8) << 3) + (d0a & 7);
        const int sdb = (((d0b >> 3) ^ cs8) << 3) + (d0b & 7);

        bf16x8 qb4[4], ka[4], va[2][2];

        // Q stage: write [64tok][32d] chunk-swz from acc[0..1], read q B-frags
        #pragma unroll
        for (int it = 0; it < 2; it++) {
            float4 bv = *(const float4*)&qkv_b[w * 32 + it * 16 + d0a];
            int sd = it ? sdb : sda;
            #pragma unroll
            for (int j = 0; j < 4; j++) {
                f32x4 a = acc[it][j];
                unsigned* dst = (unsigned*)&SW[(j * 16 + l15) * 32 + sd];
                dst[0] = pk2(a[0] + bv.x, a[1] + bv.y);
                dst[1] = pk2(a[2] + bv.z, a[3] + bv.w);
            }
        }
        #pragma unroll
        for (int nt = 0; nt < 4; nt++)
            qb4[nt] = *(const bf16x8*)&SW[(nt * 16 + l15) * 32 + swz];

        // K stage: overwrite same region from acc[2..3], read k A-frags
        #pragma unroll
        for (int it = 0; it < 2; it++) {
            float4 bv = *(const float4*)&qkv_b[256 + w * 32 + it * 16 + d0a];
            int sd = it ? sdb : sda;
            #pragma unroll
            for (int j = 0; j < 4; j++) {
                f32x4 a = acc[2 + it][j];
                unsigned* dst = (unsigned*)&SW[(j * 16 + l15) * 32 + sd];
                dst[0] = pk2(a[0] + bv.x, a[1] + bv.y);
                dst[1] = pk2(a[2] + bv.z, a[3] + bv.w);
            }
        }
        #pragma unroll
        for (int mt = 0; mt < 4; mt++)
            ka[mt] = *(const bf16x8*)&SW[(mt * 16 + l15) * 32 + swz];

        // V stage: overwrite with V^T [32d][72tok] from acc[4..5], read v A-frags
        #pragma unroll
        for (int it = 0; it < 2; it++) {
            float4 bv = *(const float4*)&qkv_b[512 + w * 32 + it * 16 + d0a];
            int d0 = it * 16 + d0a;
            #pragma unroll
            for (int j = 0; j < 4; j++) {
                int tok = j * 16 + l15;
                f32x4 a = acc[4 + it][j];
                SW[(d0 + 0) * 72 + tok] = (short)f2bf(a[0] + bv.x);
                SW[(d0 + 1) * 72 + tok] = (short)f2bf(a[1] + bv.y);
                SW[(d0 + 2) * 72 + tok] = (short)f2bf(a[2] + bv.z);
                SW[(d0 + 3) * 72 + tok] = (short)f2bf(a[3] + bv.w);
            }
        }
        #pragma unroll
        for (int dt = 0; dt < 2; dt++)
            #pragma unroll
            for (int kk = 0; kk < 2; kk++)
                va[dt][kk] = *(const bf16x8*)&SW[(dt * 16 + l15) * 72 + kk * 32 + g * 8];

        // attention: P scratch reuses SW[0..1152)
        short* Plw = SW;
        short* AOw = &smem[AO_OFF + h * 2048];    // AO [h][tok][32] chunk-swz
        const float* rh = &rpbs[h * 169];
        const float scale = 0.17677669529663687f; // 1/sqrt(32)

        #pragma unroll
        for (int nt = 0; nt < 4; nt++) {
            f32x4 s4[4];
            #pragma unroll
            for (int mt = 0; mt < 4; mt++)
                s4[mt] = __builtin_amdgcn_mfma_f32_16x16x32_bf16(ka[mt], qb4[nt], zero, 0, 0, 0);
            int n = nt * 16 + l15;
            int ni = n / 7;
            int an = 13 * ni + (n - 7 * ni) + 84;
            #pragma unroll
            for (int mt = 0; mt < 4; mt++)
                #pragma unroll
                for (int r = 0; r < 4; r++) {
                    int m = mt * 16 + g * 4 + r;
                    int mi = m / 7;
                    int idx = an - (13 * mi + (m - 7 * mi));
                    idx = idx < 0 ? 0 : (idx > 168 ? 168 : idx);
                    float val = s4[mt][r] * scale + rh[idx];
                    s4[mt][r] = (m < 49) ? val : -1e30f;
                }
            float tmax = -1e30f;
            #pragma unroll
            for (int mt = 0; mt < 4; mt++)
                #pragma unroll
                for (int r = 0; r < 4; r++) tmax = fmaxf(tmax, s4[mt][r]);
            tmax = fmaxf(tmax, __shfl_xor(tmax, 16));
            tmax = fmaxf(tmax, __shfl_xor(tmax, 32));
            float rsum = 0.f;
            #pragma unroll
            for (int mt = 0; mt < 4; mt++)
                #pragma unroll
                for (int r = 0; r < 4; r++) {
                    float e = __expf(s4[mt][r] - tmax);
                    s4[mt][r] = e;
                    rsum += e;
                }
            rsum += __shfl_xor(rsum, 16);
            rsum += __shfl_xor(rsum, 32);

            // P (unnormalized) -> Plw[n'][m]; wave-local, in-order LDS => no barrier
            #pragma unroll
            for (int mt = 0; mt < 4; mt++) {
                unsigned* dst = (unsigned*)&Plw[l15 * 72 + mt * 16 + g * 4];
                dst[0] = pk2(s4[mt][0], s4[mt][1]);
                dst[1] = pk2(s4[mt][2], s4[mt][3]);
            }
            bf16x8 pb0 = *(const bf16x8*)&Plw[l15 * 72 + g * 8];
            bf16x8 pb1 = *(const bf16x8*)&Plw[l15 * 72 + 32 + g * 8];
            f32x4 o0 = __builtin_amdgcn_mfma_f32_16x16x32_bf16(va[0][0], pb0, zero, 0, 0, 0);
            o0 = __builtin_amdgcn_mfma_f32_16x16x32_bf16(va[0][1], pb1, o0, 0, 0, 0);
            f32x4 o1 = __builtin_amdgcn_mfma_f32_16x16x32_bf16(va[1][0], pb0, zero, 0, 0, 0);
            o1 = __builtin_amdgcn_mfma_f32_16x16x32_bf16(va[1][1], pb1, o1, 0, 0, 0);
            float inv = 1.f / rsum;
            {
                unsigned* dst = (unsigned*)&AOw[n * 32 + sda];
                dst[0] = pk2(o0[0] * inv, o0[1] * inv);
                dst[1] = pk2(o0[2] * inv, o0[3] * inv);
            }
            {
                unsigned* dst = (unsigned*)&AOw[n * 32 + sdb];
                dst[0] = pk2(o1[0] * inv, o1[1] * inv);
                dst[1] = pk2(o1[2] * inv, o1[3] * inv);
            }
        }
    }
    __syncthreads();   // barrier #3: all heads' AO visible for proj

    // ---- phase 3: proj GEMM. Wave w computes out-feats [w*32, w*32+32).
    //      A-frags (Wp) from L2; B-frags from AO (k-step ks == head ks). ----
    {
        f32x4 acc2[2][4];
        #pragma unroll
        for (int i = 0; i < 2; i++)
            #pragma unroll
            for (int j = 0; j < 4; j++) acc2[i][j] = zero;

        const short* pbase = Wp + (size_t)(w * 32 + l15) * 256 + g * 8;
        #pragma unroll
        for (int ks = 0; ks < 8; ks++) {
            bf16x8 af2[2], bf2[4];
            af2[0] = *(const bf16x8*)(pbase + ks * 32);
            af2[1] = *(const bf16x8*)(pbase + 4096 + ks * 32);
            #pragma unroll
            for (int j = 0; j < 4; j++)
                bf2[j] = *(const bf16x8*)&smem[AO_OFF + ks * 2048 + (j * 16 + l15) * 32 + swz];
            #pragma unroll
            for (int i = 0; i < 2; i++)
                #pragma unroll
                for (int j = 0; j < 4; j++)
                    acc2[i][j] = __builtin_amdgcn_mfma_f32_16x16x32_bf16(
                        af2[i], bf2[j], acc2[i][j], 0, 0, 0);
        }
        #pragma unroll
        for (int it = 0; it < 2; it++) {
            int fo = w * 32 + it * 16 + g * 4;
            float4 bv = *(const float4*)&proj_b[fo];
            #pragma unroll
            for (int j = 0; j < 4; j++) {
                int tok = j * 16 + l15;
                if (tok < 49) {
                    f32x4 a = acc2[it][j];
                    float4 val = make_float4(a[0] + bv.x, a[1] + bv.y,
                                             a[2] + bv.z, a[3] + bv.w);
                    *(float4*)&out[((size_t)b * 49 + tok) * 256 + fo] = val;
                }
            }
        }
    }
}

extern "C" void kernel_launch(void* const* d_in, const int* in_sizes, int n_in,
                              void* d_out, int out_size, void* d_ws, size_t ws_size,
                              hipStream_t stream) {
    const float* x      = (const float*)d_in[0];
    const float* qkv_w  = (const float*)d_in[1];
    const float* qkv_b  = (const float*)d_in[2];
    const float* rpb    = (const float*)d_in[3];
    const float* proj_w = (const float*)d_in[4];
    const float* proj_b = (const float*)d_in[5];
    float* out = (float*)d_out;

    // ws (shorts): Wqkv_t[768*256] | Wproj_t[256*256]
    short* Wqkv_t  = (short*)d_ws;
    short* Wproj_t = Wqkv_t + 768 * 256;
    if (ws_size < 524288ull) return;

    k_prep<<<1024, 256, 0, stream>>>(qkv_w, proj_w, Wqkv_t, Wproj_t);
    k_fused<<<4096, 512, 0, stream>>>(x, Wqkv_t, Wproj_t, qkv_b, rpb, proj_b, out);
}

// Round 6
// 583.197 us; speedup vs baseline: 1.9373x; 1.9373x over previous
//
#include <hip/hip_runtime.h>
#include <stdint.h>

// Window attention, Swin-style. B=4096 windows, N=49, C=256, NH=8, D=32.
// FULLY FUSED v5: one block per window (512 thr, 8 waves), wave w owns head w.
// Weights stream from L2 straight into MFMA fragments (no staging LDS).
// Phase 1 split into 3 sequential passes (Q,K,V) of acc[2][4] each to keep
// peak regs <=128/lane (v4 spilled 2.4GB of scratch at the 4-waves/SIMD cap).
// LDS ~73 KB -> 2 blocks/CU, 4 waves/SIMD. 3 barriers total.

typedef __attribute__((ext_vector_type(8))) short bf16x8;
typedef __attribute__((ext_vector_type(4))) float f32x4;

__device__ __forceinline__ unsigned short f2bf(float f) {
    unsigned u = __float_as_uint(f);
    u += 0x7fffu + ((u >> 16) & 1u);   // RNE
    return (unsigned short)(u >> 16);
}
__device__ __forceinline__ unsigned pk2(float a, float b) {
    return (unsigned)f2bf(a) | ((unsigned)f2bf(b) << 16);
}

// ---- K0: weights fp32 -> bf16, transposed to [feat][k] (B^T) layout ----
__global__ void k_prep(const float* __restrict__ qkv_w, const float* __restrict__ proj_w,
                       short* __restrict__ Wqkv_t, short* __restrict__ Wproj_t) {
    int tid = blockIdx.x * 256 + threadIdx.x;   // 262144 total
    if (tid < 196608) {                          // 768*256
        int nn = tid >> 8, kk = tid & 255;
        Wqkv_t[tid] = (short)f2bf(qkv_w[kk * 768 + nn]);
    } else {
        int t2 = tid - 196608;                   // 256*256
        int nn = t2 >> 8, kk = t2 & 255;
        Wproj_t[t2] = (short)f2bf(proj_w[kk * 256 + nn]);
    }
}

// LDS map (shorts). Total 34816 shorts (69632 B) + rpbs 5408 B = 75040 B -> 2 blocks/CU.
//   XS @ 0      [64tok][256k] (chunk-swz) 32 KB   } aliased: XS dead after phase-1
//   AO @ 0      [8h][64tok][32d] (chunk-swz)      } passes (barrier #2 separates)
//   SW @ 16384  per-wave 2304-short scratch, time-shared:
//               Q[64][32] -> q-frags -> K[64][32] -> k-frags
//               -> V^T[32][72] -> v-frags -> P[16][72]
#define XS_OFF 0
#define AO_OFF 0
#define SW_OFF 16384

// One QKV sub-GEMM pass: part P (0=Q,1=K,2=V), 32 feats x 64 tok x K=256.
#define QKV_PASS(P, ACC)                                                          \
    {                                                                             \
        const short* wb = Wq + (size_t)((P) * 256 + w * 32 + l15) * 256 + g * 8;  \
        _Pragma("unroll")                                                         \
        for (int ks = 0; ks < 8; ks++) {                                          \
            bf16x8 af0 = *(const bf16x8*)(wb + ks * 32);                          \
            bf16x8 af1 = *(const bf16x8*)(wb + 4096 + ks * 32);                   \
            int xsl = (((ks << 2) + g) ^ (l15 & 7)) << 3;                         \
            _Pragma("unroll")                                                     \
            for (int j = 0; j < 4; j++) {                                         \
                bf16x8 bfj = *(const bf16x8*)&smem[XS_OFF + (j * 16 + l15) * 256 + xsl]; \
                ACC[0][j] = __builtin_amdgcn_mfma_f32_16x16x32_bf16(af0, bfj, ACC[0][j], 0, 0, 0); \
                ACC[1][j] = __builtin_amdgcn_mfma_f32_16x16x32_bf16(af1, bfj, ACC[1][j], 0, 0, 0); \
            }                                                                     \
        }                                                                         \
    }

__global__ __launch_bounds__(512, 4) void k_fused(
        const float* __restrict__ x, const short* __restrict__ Wq,
        const short* __restrict__ Wp, const float* __restrict__ qkv_b,
        const float* __restrict__ rpb, const float* __restrict__ proj_b,
        float* __restrict__ out) {
    __shared__ __align__(16) short smem[34816];
    __shared__ float rpbs[1352];               // [8h][169] per-head contiguous

    const int b = blockIdx.x;
    const int t = threadIdx.x;
    const int w = t >> 6, lane = t & 63;
    const int l15 = lane & 15, g = lane >> 4;
    const int cs8 = (l15 >> 1) & 3;               // chunk-swz field for 32-short rows
    const int swz = (g ^ cs8) << 3;               // swizzled frag chunk offset

    f32x4 zero = {0.f, 0.f, 0.f, 0.f};

    // ---- phase 0: rpb -> LDS (transposed to [h][169]); x fp32 -> bf16 -> XS ----
    for (int i = t; i < 1352; i += 512) rpbs[(i & 7) * 169 + (i >> 3)] = rpb[i];
    #pragma unroll
    for (int i = 0; i < 4; i++) {
        int cid = t + i * 512;                    // 2048 granules = 64 tok x 32 chunks
        int tok = cid >> 5, c = cid & 31;
        uint4 w4 = make_uint4(0u, 0u, 0u, 0u);
        if (tok < 49) {
            const float4* s = (const float4*)(x + ((size_t)b * 49 + tok) * 256 + c * 8);
            float4 f0 = s[0], f1 = s[1];
            w4 = make_uint4(pk2(f0.x, f0.y), pk2(f0.z, f0.w),
                            pk2(f1.x, f1.y), pk2(f1.z, f1.w));
        }
        *(uint4*)&smem[XS_OFF + tok * 256 + ((c ^ (tok & 7)) << 3)] = w4;
    }
    __syncthreads();   // barrier #1: XS + rpbs visible

    // ---- phase 1: three low-pressure passes. Wave w = head w.
    //      Each pass: acc[2][4] (32 regs) -> stage into SW -> read frags. ----
    short* SW = &smem[SW_OFF + w * 2304];         // per-wave scratch
    const int d0a = g * 4;                        // it=0 feature base
    const int d0b = 16 + g * 4;                   // it=1 feature base
    const int sda = (((d0a >> 3) ^ cs8) << 3) + (d0a & 7);
    const int sdb = (((d0b >> 3) ^ cs8) << 3) + (d0b & 7);

    bf16x8 qb4[4], ka[4], va[2][2];

    {   // --- Q pass ---
        f32x4 aq[2][4];
        #pragma unroll
        for (int i = 0; i < 2; i++)
            #pragma unroll
            for (int j = 0; j < 4; j++) aq[i][j] = zero;
        QKV_PASS(0, aq)
        #pragma unroll
        for (int it = 0; it < 2; it++) {
            float4 bv = *(const float4*)&qkv_b[w * 32 + it * 16 + d0a];
            int sd = it ? sdb : sda;
            #pragma unroll
            for (int j = 0; j < 4; j++) {
                f32x4 a = aq[it][j];
                unsigned* dst = (unsigned*)&SW[(j * 16 + l15) * 32 + sd];
                dst[0] = pk2(a[0] + bv.x, a[1] + bv.y);
                dst[1] = pk2(a[2] + bv.z, a[3] + bv.w);
            }
        }
        #pragma unroll
        for (int nt = 0; nt < 4; nt++)
            qb4[nt] = *(const bf16x8*)&SW[(nt * 16 + l15) * 32 + swz];
    }
    {   // --- K pass (overwrites SW) ---
        f32x4 ak[2][4];
        #pragma unroll
        for (int i = 0; i < 2; i++)
            #pragma unroll
            for (int j = 0; j < 4; j++) ak[i][j] = zero;
        QKV_PASS(1, ak)
        #pragma unroll
        for (int it = 0; it < 2; it++) {
            float4 bv = *(const float4*)&qkv_b[256 + w * 32 + it * 16 + d0a];
            int sd = it ? sdb : sda;
            #pragma unroll
            for (int j = 0; j < 4; j++) {
                f32x4 a = ak[it][j];
                unsigned* dst = (unsigned*)&SW[(j * 16 + l15) * 32 + sd];
                dst[0] = pk2(a[0] + bv.x, a[1] + bv.y);
                dst[1] = pk2(a[2] + bv.z, a[3] + bv.w);
            }
        }
        #pragma unroll
        for (int mt = 0; mt < 4; mt++)
            ka[mt] = *(const bf16x8*)&SW[(mt * 16 + l15) * 32 + swz];
    }
    {   // --- V pass (overwrites SW with V^T [32d][72tok]) ---
        f32x4 av[2][4];
        #pragma unroll
        for (int i = 0; i < 2; i++)
            #pragma unroll
            for (int j = 0; j < 4; j++) av[i][j] = zero;
        QKV_PASS(2, av)
        #pragma unroll
        for (int it = 0; it < 2; it++) {
            float4 bv = *(const float4*)&qkv_b[512 + w * 32 + it * 16 + d0a];
            int d0 = it * 16 + d0a;
            #pragma unroll
            for (int j = 0; j < 4; j++) {
                int tok = j * 16 + l15;
                f32x4 a = av[it][j];
                SW[(d0 + 0) * 72 + tok] = (short)f2bf(a[0] + bv.x);
                SW[(d0 + 1) * 72 + tok] = (short)f2bf(a[1] + bv.y);
                SW[(d0 + 2) * 72 + tok] = (short)f2bf(a[2] + bv.z);
                SW[(d0 + 3) * 72 + tok] = (short)f2bf(a[3] + bv.w);
            }
        }
        #pragma unroll
        for (int dt = 0; dt < 2; dt++)
            #pragma unroll
            for (int kk = 0; kk < 2; kk++)
                va[dt][kk] = *(const bf16x8*)&SW[(dt * 16 + l15) * 72 + kk * 32 + g * 8];
    }
    __syncthreads();   // barrier #2: all XS reads done (AO aliases XS below)

    // ---- phase 2: attention, fully wave-local (head h = w), no barriers ----
    {
        const int h = w;
        short* Plw = SW;                          // P scratch reuses SW[0..1152)
        short* AOw = &smem[AO_OFF + h * 2048];    // AO [h][tok][32] chunk-swz
        const float* rh = &rpbs[h * 169];
        const float scale = 0.17677669529663687f; // 1/sqrt(32)

        #pragma unroll
        for (int nt = 0; nt < 4; nt++) {
            f32x4 s4[4];
            #pragma unroll
            for (int mt = 0; mt < 4; mt++)
                s4[mt] = __builtin_amdgcn_mfma_f32_16x16x32_bf16(ka[mt], qb4[nt], zero, 0, 0, 0);
            int n = nt * 16 + l15;
            int ni = n / 7;
            int an = 13 * ni + (n - 7 * ni) + 84;
            #pragma unroll
            for (int mt = 0; mt < 4; mt++)
                #pragma unroll
                for (int r = 0; r < 4; r++) {
                    int m = mt * 16 + g * 4 + r;
                    int mi = m / 7;
                    int idx = an - (13 * mi + (m - 7 * mi));
                    idx = idx < 0 ? 0 : (idx > 168 ? 168 : idx);
                    float val = s4[mt][r] * scale + rh[idx];
                    s4[mt][r] = (m < 49) ? val : -1e30f;
                }
            float tmax = -1e30f;
            #pragma unroll
            for (int mt = 0; mt < 4; mt++)
                #pragma unroll
                for (int r = 0; r < 4; r++) tmax = fmaxf(tmax, s4[mt][r]);
            tmax = fmaxf(tmax, __shfl_xor(tmax, 16));
            tmax = fmaxf(tmax, __shfl_xor(tmax, 32));
            float rsum = 0.f;
            #pragma unroll
            for (int mt = 0; mt < 4; mt++)
                #pragma unroll
                for (int r = 0; r < 4; r++) {
                    float e = __expf(s4[mt][r] - tmax);
                    s4[mt][r] = e;
                    rsum += e;
                }
            rsum += __shfl_xor(rsum, 16);
            rsum += __shfl_xor(rsum, 32);

            // P (unnormalized) -> Plw[n'][m]; wave-local, in-order LDS => no barrier
            #pragma unroll
            for (int mt = 0; mt < 4; mt++) {
                unsigned* dst = (unsigned*)&Plw[l15 * 72 + mt * 16 + g * 4];
                dst[0] = pk2(s4[mt][0], s4[mt][1]);
                dst[1] = pk2(s4[mt][2], s4[mt][3]);
            }
            bf16x8 pb0 = *(const bf16x8*)&Plw[l15 * 72 + g * 8];
            bf16x8 pb1 = *(const bf16x8*)&Plw[l15 * 72 + 32 + g * 8];
            f32x4 o0 = __builtin_amdgcn_mfma_f32_16x16x32_bf16(va[0][0], pb0, zero, 0, 0, 0);
            o0 = __builtin_amdgcn_mfma_f32_16x16x32_bf16(va[0][1], pb1, o0, 0, 0, 0);
            f32x4 o1 = __builtin_amdgcn_mfma_f32_16x16x32_bf16(va[1][0], pb0, zero, 0, 0, 0);
            o1 = __builtin_amdgcn_mfma_f32_16x16x32_bf16(va[1][1], pb1, o1, 0, 0, 0);
            float inv = 1.f / rsum;
            {
                unsigned* dst = (unsigned*)&AOw[n * 32 + sda];
                dst[0] = pk2(o0[0] * inv, o0[1] * inv);
                dst[1] = pk2(o0[2] * inv, o0[3] * inv);
            }
            {
                unsigned* dst = (unsigned*)&AOw[n * 32 + sdb];
                dst[0] = pk2(o1[0] * inv, o1[1] * inv);
                dst[1] = pk2(o1[2] * inv, o1[3] * inv);
            }
        }
    }
    __syncthreads();   // barrier #3: all heads' AO visible for proj

    // ---- phase 3: proj GEMM. Wave w computes out-feats [w*32, w*32+32).
    //      A-frags (Wp) from L2; B-frags from AO (k-step ks == head ks). ----
    {
        f32x4 acc2[2][4];
        #pragma unroll
        for (int i = 0; i < 2; i++)
            #pragma unroll
            for (int j = 0; j < 4; j++) acc2[i][j] = zero;

        const short* pbase = Wp + (size_t)(w * 32 + l15) * 256 + g * 8;
        #pragma unroll
        for (int ks = 0; ks < 8; ks++) {
            bf16x8 af2[2], bf2[4];
            af2[0] = *(const bf16x8*)(pbase + ks * 32);
            af2[1] = *(const bf16x8*)(pbase + 4096 + ks * 32);
            #pragma unroll
            for (int j = 0; j < 4; j++)
                bf2[j] = *(const bf16x8*)&smem[AO_OFF + ks * 2048 + (j * 16 + l15) * 32 + swz];
            #pragma unroll
            for (int i = 0; i < 2; i++)
                #pragma unroll
                for (int j = 0; j < 4; j++)
                    acc2[i][j] = __builtin_amdgcn_mfma_f32_16x16x32_bf16(
                        af2[i], bf2[j], acc2[i][j], 0, 0, 0);
        }
        #pragma unroll
        for (int it = 0; it < 2; it++) {
            int fo = w * 32 + it * 16 + g * 4;
            float4 bv = *(const float4*)&proj_b[fo];
            #pragma unroll
            for (int j = 0; j < 4; j++) {
                int tok = j * 16 + l15;
                if (tok < 49) {
                    f32x4 a = acc2[it][j];
                    float4 val = make_float4(a[0] + bv.x, a[1] + bv.y,
                                             a[2] + bv.z, a[3] + bv.w);
                    *(float4*)&out[((size_t)b * 49 + tok) * 256 + fo] = val;
                }
            }
        }
    }
}

extern "C" void kernel_launch(void* const* d_in, const int* in_sizes, int n_in,
                              void* d_out, int out_size, void* d_ws, size_t ws_size,
                              hipStream_t stream) {
    const float* x      = (const float*)d_in[0];
    const float* qkv_w  = (const float*)d_in[1];
    const float* qkv_b  = (const float*)d_in[2];
    const float* rpb    = (const float*)d_in[3];
    const float* proj_w = (const float*)d_in[4];
    const float* proj_b = (const float*)d_in[5];
    float* out = (float*)d_out;

    // ws (shorts): Wqkv_t[768*256] | Wproj_t[256*256]
    short* Wqkv_t  = (short*)d_ws;
    short* Wproj_t = Wqkv_t + 768 * 256;
    if (ws_size < 524288ull) return;

    k_prep<<<1024, 256, 0, stream>>>(qkv_w, proj_w, Wqkv_t, Wproj_t);
    k_fused<<<4096, 512, 0, stream>>>(x, Wqkv_t, Wproj_t, qkv_b, rpb, proj_b, out);
}